// Round 8
// baseline (281.894 us; speedup 1.0000x reference)
//
#include <hip/hip_runtime.h>

#define NN 20000
#define NNP 20096       // padded rows: 314*64
#define NEIGH 12
#define NCRYS 20
#define MT2 1256        // padded M row-tiles of 16
#define NSUB 16         // pooled partial-sum split

typedef __bf16 bf16x8 __attribute__((ext_vector_type(8)));
typedef __bf16 bf16x4 __attribute__((ext_vector_type(4)));
typedef float f32x4 __attribute__((ext_vector_type(4)));

// ============================================================
// pack: W[k][n] -> bf16 MFMA-B frag layout Wp[kt][nt][k8][ni][j]
// KV = valid K (k >= KV packs 0 — used to pad bond K 480->512)
// ============================================================
__device__ __forceinline__ void pack_one(const float* Wrel, const float* Wroot,
                                         __bf16* Wp, int K, int KV, int idx) {
    int k = idx >> 8, n = idx & 255;
    int r = n >> 6, h = n & 63;
    float v = 0.f;
    if (k < KV)
        v = (r < 3) ? Wrel[((size_t)r * KV + k) * 64 + h] : Wroot[(size_t)k * 64 + h];
    int kt = k >> 5, k8 = (k >> 3) & 3, j = k & 7, nt = n >> 4, ni = n & 15;
    Wp[((((size_t)kt * 16 + nt) * 4 + k8) * 16 + ni) * 8 + j] = (__bf16)v;
}

// ============================================================
// setup: build_adj (938) + pack (256, strided) + transpose (628)
// ============================================================
__global__ __launch_bounds__(256) void setup_kernel(
    const int* __restrict__ species, const int* __restrict__ nbr,
    int* __restrict__ adj, int* __restrict__ deg,
    const float* __restrict__ W1b_rel, const float* __restrict__ W1b_root,
    const float* __restrict__ W1a_rel, const float* __restrict__ W1a_root,
    const float* __restrict__ W2b_rel, const float* __restrict__ W2b_root,
    const float* __restrict__ W2a_rel, const float* __restrict__ W2a_root,
    __bf16* __restrict__ Wp1b, __bf16* __restrict__ Wp1a,
    __bf16* __restrict__ Wp2b, __bf16* __restrict__ Wp2a,
    const float* __restrict__ bond, const float* __restrict__ angle,
    float* __restrict__ bondT, float* __restrict__ angleT) {
    __shared__ float ls[64 * 145];
    const int bx = blockIdx.x, tid = threadIdx.x;
    if (bx < 938) {
        int e = bx * 256 + tid;
        if (e < NN * NEIGH) {
            int i = e / NEIGH;
            int d = nbr[e];
            int r = species[i] + species[d];
            int slot = atomicAdd(&deg[d], 1);
            if (slot < 64) adj[(size_t)d * 64 + slot] = i | (r << 28);
        }
    } else if (bx < 938 + 256) {
        const int S0 = 512 * 256, S1 = S0 + 2880 * 256, S2 = S1 + 64 * 256, S3 = S2 + 64 * 256;
        for (int idx = (bx - 938) * 256 + tid; idx < S3; idx += 256 * 256) {
            if (idx < S0)       pack_one(W1b_rel, W1b_root, Wp1b, 512, 480, idx);
            else if (idx < S1)  pack_one(W1a_rel, W1a_root, Wp1a, 2880, 2880, idx - S0);
            else if (idx < S2)  pack_one(W2b_rel, W2b_root, Wp2b, 64, 64, idx - S1);
            else                pack_one(W2a_rel, W2a_root, Wp2a, 64, 64, idx - S2);
        }
    } else {
        int tb = bx - 1194;
        if (tb < 314) {
            int m0 = tb * 64;
            for (int idx = tid; idx < 64 * 144; idx += 256) {
                int mm = idx / 144, j = idx - mm * 144;
                int m = m0 + mm;
                ls[mm * 145 + j] = (m < NN) ? angle[(size_t)m * 144 + j] : 0.f;
            }
            __syncthreads();
            for (int idx = tid; idx < 144 * 64; idx += 256) {
                int j = idx >> 6, mm = idx & 63;
                angleT[(size_t)j * NNP + m0 + mm] = ls[mm * 145 + j];
            }
        } else {
            int m0 = (tb - 314) * 64;
            for (int idx = tid; idx < 64 * 12; idx += 256) {
                int mm = idx / 12, j = idx - mm * 12;
                int m = m0 + mm;
                ls[mm * 13 + j] = (m < NN) ? bond[(size_t)m * 12 + j] : 0.f;
            }
            __syncthreads();
            for (int idx = tid; idx < 13 * 64; idx += 256) {  // row 12 = zero pad
                int j = idx >> 6, mm = idx & 63;
                bondT[(size_t)j * NNP + m0 + mm] = (j < 12) ? ls[mm * 13 + j] : 0.f;
            }
        }
    }
}

// ============================================================
// gemm1: 64x256 tile, 512 threads (8 waves, each 64r x 32c).
// BK=64 (2 subtiles of 32 per barrier): 16 MFMA/wave/barrier.
// A: gbf recurrence -> 16KB LDS ping-pong; exps once per element.
// B: global->frag regs (packed layout = frag layout), depth-1 prefetch.
// All K-loop addressing is incremental (no div/mul on the hot path).
// ============================================================
template <int MODE>  // 0: bond K=512(pad) DIVN=40; 1: angle K=2880 DIVN=20
__device__ __forceinline__ void gemm1_body(const float* __restrict__ xT,
                                           const __bf16* __restrict__ Wp,
                                           float* __restrict__ Y, int mb,
                                           __bf16* __restrict__ Al) {
    constexpr int NKT2 = (MODE == 0) ? 8 : 45;    // barriers (BK=64)
    constexpr int DIVN = (MODE == 0) ? 40 : 20;
    constexpr int DS   = (MODE == 0) ? 24 : 4;    // 64 % DIVN
    constexpr int DJR  = (MODE == 0) ? 1 : 3;     // 64 / DIVN
    constexpr float F0 = (MODE == 0) ? 0.f : -1.f;
    constexpr float FS = (MODE == 0) ? (8.f / 39.f) : (2.f / 19.f);
    constexpr float NG2 = ((MODE == 0) ? -25.f : -100.f) * 1.44269504f;
    const float C  = __builtin_amdgcn_exp2f(2.f * NG2 * FS * FS);
    const float P1 = NG2 * FS * FS;
    const float P2 = -2.f * NG2 * FS;

    const int tid = threadIdx.x;
    const int lane = tid & 63, wv = tid >> 6;
    const int m0 = mb * 64;
    // staging role: thread -> one 4-elem chunk in each of the 2 subtiles
    const int smt = tid >> 7, sk8 = (tid >> 5) & 3;
    const int smi = (tid >> 1) & 15, sjh = (tid & 1) * 4;
    const int sgm = m0 + smt * 16 + smi;
    const int kk0 = sk8 * 8 + sjh;
    const int swoff = ((smt * 4 + sk8) * 16 + smi) * 8 + sjh;
    // MFMA frag role
    const int k8b = lane >> 4, nib = lane & 15;
    const bf16x8* Bg = (const bf16x8*)Wp;

    // chunk states: c0 at k=kt*64+kk0, c1 at +32
    int s0 = kk0 % DIVN, s1 = (kk0 + 32) % DIVN;
    int off0 = (kk0 / DIVN) * NNP + sgm;
    int off1 = ((kk0 + 32) / DIVN) * NNP + sgm;
    int bidx = ((wv * 2) * 4 + k8b) * 16 + nib;   // (kt32=0, jf=0) frag index

    f32x4 acc[4][2] = {};
    bf16x8 bcur[4], bnx[4];

    auto gbf4s = [&](float a, int s) -> bf16x4 {
        float f = fmaf((float)s, FS, F0);
        float d0 = a - f;
        float e0 = __builtin_amdgcn_exp2f(NG2 * d0 * d0);
        float q0 = __builtin_amdgcn_exp2f(fmaf(P2, d0, P1));
        float e1 = e0 * q0;
        float q1 = q0 * C;
        float e2 = e1 * q1;
        float e3 = e2 * q1 * C;
        bf16x4 v;
        v[0] = (__bf16)e0; v[1] = (__bf16)e1; v[2] = (__bf16)e2; v[3] = (__bf16)e3;
        return v;
    };
    auto adv = [&]() {  // advance both chunk states by K+=64
        s0 += DS; off0 += DJR * NNP; if (s0 >= DIVN) { s0 -= DIVN; off0 += NNP; }
        s1 += DS; off1 += DJR * NNP; if (s1 >= DIVN) { s1 -= DIVN; off1 += NNP; }
    };

    // ---- prologue: barrier-tile 0 ----
    {
        float a0 = xT[off0], a1 = xT[off1];
#pragma unroll
        for (int sub = 0; sub < 2; ++sub)
#pragma unroll
            for (int jf = 0; jf < 2; ++jf)
                bcur[sub * 2 + jf] = Bg[bidx + sub * 1024 + jf * 64];
        *(bf16x4*)&Al[swoff] = gbf4s(a0, s0);
        *(bf16x4*)&Al[2048 + swoff] = gbf4s(a1, s1);
        adv();               // states -> tile 1
        bidx += 2048;
    }
    __syncthreads();

    for (int kt = 0; kt < NKT2; ++kt) {
        __bf16* Ab = Al + ((kt & 1) << 12);
        __bf16* An = Al + (((kt & 1) ^ 1) << 12);
        const bool more = (kt + 1 < NKT2);
        float an0, an1;
        int cs0 = s0, cs1 = s1;
        if (more) {
            an0 = xT[off0];                        // next tile a (in flight)
            an1 = xT[off1];
#pragma unroll
            for (int sub = 0; sub < 2; ++sub)
#pragma unroll
                for (int jf = 0; jf < 2; ++jf)
                    bnx[sub * 2 + jf] = Bg[bidx + sub * 1024 + jf * 64];
            adv();
            bidx += 2048;
        }
        // ---- 16 MFMA on current buffer ----
#pragma unroll
        for (int sub = 0; sub < 2; ++sub) {
            bf16x8 af[4];
#pragma unroll
            for (int t = 0; t < 4; ++t)
                af[t] = *(const bf16x8*)&Ab[(sub << 11) + ((((t << 2) + k8b) << 4) + nib) * 8];
#pragma unroll
            for (int i = 0; i < 4; ++i)
#pragma unroll
                for (int j = 0; j < 2; ++j)
                    acc[i][j] = __builtin_amdgcn_mfma_f32_16x16x32_bf16(af[i], bcur[sub * 2 + j], acc[i][j], 0, 0, 0);
        }
        // ---- stage next tile while the matrix pipe drains ----
        if (more) {
            *(bf16x4*)&An[swoff] = gbf4s(an0, cs0);
            *(bf16x4*)&An[2048 + swoff] = gbf4s(an1, cs1);
        }
        __syncthreads();
        if (more) {
#pragma unroll
            for (int q = 0; q < 4; ++q) bcur[q] = bnx[q];
        }
    }

    // ---- epilogue: C/D layout col=lane&15, row=(lane>>4)*4+reg; f32 out ----
    const int mrow0 = m0 + ((lane >> 4) << 2);
    const int ncol = (wv << 5) + nib;
#pragma unroll
    for (int i = 0; i < 4; ++i)
#pragma unroll
        for (int j = 0; j < 2; ++j)
#pragma unroll
            for (int v = 0; v < 4; ++v) {
                int m = mrow0 + i * 16 + v;
                if (m < NN) Y[(size_t)m * 256 + ncol + j * 16] = acc[i][j][v];
            }
}

// even bx -> angle, odd bx -> bond: every CU gets a balanced mix
__global__ __launch_bounds__(512, 4) void mega_gemm1(const float* __restrict__ bondT,
                                                     const float* __restrict__ angleT,
                                                     const __bf16* __restrict__ Wp1b,
                                                     const __bf16* __restrict__ Wp1a,
                                                     float* __restrict__ Yb, float* __restrict__ Ya) {
    __shared__ __align__(16) __bf16 Al[2 * 4096];
    int bx = blockIdx.x;
    if ((bx & 1) == 0) gemm1_body<1>(angleT, Wp1a, Ya, bx >> 1, Al);
    else               gemm1_body<0>(bondT, Wp1b, Yb, bx >> 1, Al);
}

// ============================================================
// Dense layer-2 GEMM, both chains. K=64, A pre-packed bf16, f32 out
// ============================================================
__global__ __launch_bounds__(256) void mega_gemm2(const __bf16* __restrict__ Hbp,
                                                  const __bf16* __restrict__ Hap,
                                                  const __bf16* __restrict__ Wp2b,
                                                  const __bf16* __restrict__ Wp2a,
                                                  float* __restrict__ Yb, float* __restrict__ Ya) {
    __shared__ __align__(16) __bf16 Al[4096];
    __shared__ __align__(16) __bf16 Bl[4096];
    const int ch = blockIdx.x & 1;
    const int mb = blockIdx.x >> 1;
    const int nb = blockIdx.y;
    const __bf16* Ap = ch ? Hap : Hbp;
    const __bf16* Wp = ch ? Wp2a : Wp2b;
    float* Y = ch ? Ya : Yb;
    const int tid = threadIdx.x;
    const int lane = tid & 63, wv = tid >> 6;
    const int m0 = mb * 128;
    const int rw = wv & 1, cw = wv >> 1;
    f32x4 acc[4][4] = {};
#pragma unroll
    for (int kt = 0; kt < 2; ++kt) {
        __syncthreads();
        {
            const float4* src = (const float4*)(Wp + (((size_t)kt * 16 + nb * 8) << 9));
            float4* dst = (float4*)Bl;
            float4 v0 = src[tid], v1 = src[tid + 256];
            dst[tid] = v0;
            dst[tid + 256] = v1;
        }
        {
            const float4* src = (const float4*)(Ap + (((size_t)kt * MT2 + mb * 8) << 9));
            float4* dst = (float4*)Al;
            float4 v0 = src[tid], v1 = src[tid + 256];
            dst[tid] = v0;
            dst[tid + 256] = v1;
        }
        __syncthreads();
        bf16x8 af[4], bfr[4];
        int fro = ((lane >> 4) << 4) + (lane & 15);
#pragma unroll
        for (int t4 = 0; t4 < 4; ++t4) {
            af[t4] = *(const bf16x8*)&Al[((((rw * 4 + t4) << 6) + fro) << 3)];
            bfr[t4] = *(const bf16x8*)&Bl[((((cw * 4 + t4) << 6) + fro) << 3)];
        }
#pragma unroll
        for (int i = 0; i < 4; ++i)
#pragma unroll
            for (int j = 0; j < 4; ++j)
                acc[i][j] = __builtin_amdgcn_mfma_f32_16x16x32_bf16(af[i], bfr[j], acc[i][j], 0, 0, 0);
    }
    const int n0 = nb * 128 + cw * 64;
    const int mrow0 = m0 + rw * 64 + ((lane >> 4) << 2);
    const int ncol = n0 + (lane & 15);
#pragma unroll
    for (int i = 0; i < 4; ++i)
#pragma unroll
        for (int j = 0; j < 4; ++j)
#pragma unroll
            for (int v = 0; v < 4; ++v) {
                int m = mrow0 + i * 16 + v;
                if (m < NN) Y[(size_t)m * 256 + ncol + j * 16] = acc[i][j][v];
            }
}

// ============================================================
// agg core: scalar (readlane) addresses + 16-batched gathers
// ============================================================
__device__ __forceinline__ float agg_node(const float* __restrict__ Y,
                                          const int* __restrict__ adj,
                                          const int* __restrict__ deg,
                                          const float* __restrict__ bias,
                                          int node, int h) {
    int dg = min(deg[node], 64);
    int e = adj[(size_t)node * 64 + h];
    bool val = h < dg;
    int r = e >> 28;
    unsigned long long bl0 = __ballot(val && r == 0);
    unsigned long long bl1 = __ballot(val && r == 1);
    unsigned long long bl2 = __ballot(val && r == 2);
    int c0 = __popcll(bl0), c1 = __popcll(bl1), c2 = __popcll(bl2);
    float s0 = 0.f, s1 = 0.f, s2 = 0.f;
    if (dg > 0) {
        int e0 = __builtin_amdgcn_readfirstlane(e);
        int ec = val ? e : e0;
        for (int k0 = 0; k0 < dg; k0 += 16) {
            float v[16];
#pragma unroll
            for (int i = 0; i < 16; ++i) {
                int ek = __builtin_amdgcn_readlane(ec, k0 + i);
                v[i] = Y[(size_t)(ek & 0x0FFFFFFF) * 256 + (ek >> 28) * 64 + h];
            }
#pragma unroll
            for (int i = 0; i < 16; ++i) {
                int kk = k0 + i;
                if (kk < dg) {
                    int rr = __builtin_amdgcn_readlane(ec, kk) >> 28;
                    if (rr == 0) s0 += v[i];
                    else if (rr == 1) s1 += v[i];
                    else s2 += v[i];
                }
            }
        }
    }
    float o = Y[(size_t)node * 256 + 192 + h] + bias[h] +
              s0 / fmaxf((float)c0, 1.f) + s1 / fmaxf((float)c1, 1.f) +
              s2 / fmaxf((float)c2, 1.f);
    return fmaxf(o, 0.f);
}

// layer-1 agg -> bf16 packed-A frag layout (feeds mega_gemm2)
__global__ __launch_bounds__(256) void agg_packed(const float* __restrict__ Yb,
                                                  const float* __restrict__ Ya,
                                                  const int* __restrict__ adj,
                                                  const int* __restrict__ deg,
                                                  const float* __restrict__ biasb,
                                                  const float* __restrict__ biasa,
                                                  __bf16* __restrict__ outb,
                                                  __bf16* __restrict__ outa) {
    const float* Y = blockIdx.y ? Ya : Yb;
    const float* bias = blockIdx.y ? biasa : biasb;
    __bf16* outp = blockIdx.y ? outa : outb;
    int node = blockIdx.x * 4 + (threadIdx.x >> 6);
    int h = threadIdx.x & 63;
    float o = (node < NN) ? agg_node(Y, adj, deg, bias, node, h) : 0.f;
    int mt = node >> 4, mi = node & 15;
    int ktt = h >> 5, k8 = (h >> 3) & 3, j = h & 7;
    outp[((((size_t)ktt * MT2 + mt) * 4 + k8) * 16 + mi) * 8 + j] = (__bf16)o;
}

// layer-2 agg fused with crystal pooling
__global__ __launch_bounds__(256) void agg_pool(const float* __restrict__ Yb,
                                                const float* __restrict__ Ya,
                                                const int* __restrict__ adj,
                                                const int* __restrict__ deg,
                                                const float* __restrict__ biasb,
                                                const float* __restrict__ biasa,
                                                const int* __restrict__ crys,
                                                float* __restrict__ pooled) {
    const float* Y = blockIdx.y ? Ya : Yb;
    const float* bias = blockIdx.y ? biasa : biasb;
    const int base = blockIdx.y ? 64 : 0;
    int node = blockIdx.x * 4 + (threadIdx.x >> 6);
    int h = threadIdx.x & 63;
    if (node >= NN) return;
    float o = agg_node(Y, adj, deg, bias, node, h);
    int c = 0;
#pragma unroll
    for (int t = 1; t < NCRYS; ++t) c += (node >= crys[t * 2]) ? 1 : 0;
    int sub = blockIdx.x & (NSUB - 1);
    atomicAdd(&pooled[((size_t)c * NSUB + sub) * 128 + base + h], o);
}

// ============================================================
// final: reduce partials, divide by count, FC
// ============================================================
__global__ void final2(const float* __restrict__ pooled, const int* __restrict__ crys,
                       const float* __restrict__ fcW, const float* __restrict__ fcb,
                       float* __restrict__ out) {
    int c = blockIdx.x >> 1, o = blockIdx.x & 1;
    int l = threadIdx.x;  // 0..63
    float cnt = (float)(crys[c * 2 + 1] - crys[c * 2]);
    float sb = 0.f, sa = 0.f;
    for (int s = 0; s < NSUB; ++s) {
        sb += pooled[((size_t)c * NSUB + s) * 128 + l];
        sa += pooled[((size_t)c * NSUB + s) * 128 + 64 + l];
    }
    float a = sb * fcW[l * 2 + o] + sa * fcW[(64 + l) * 2 + o];
    for (int s = 32; s > 0; s >>= 1) a += __shfl_down(a, s);
    if (l == 0) out[c * 2 + o] = a / cnt + fcb[o];
}

extern "C" void kernel_launch(void* const* d_in, const int* in_sizes, int n_in,
                              void* d_out, int out_size, void* d_ws, size_t ws_size,
                              hipStream_t stream) {
    const float* bond    = (const float*)d_in[0];
    const float* angle   = (const float*)d_in[1];
    const int*   species = (const int*)d_in[2];
    const int*   nbr     = (const int*)d_in[3];
    const int*   crys    = (const int*)d_in[4];
    const float* W1b_rel = (const float*)d_in[5];
    const float* W1b_root= (const float*)d_in[6];
    const float* b1b     = (const float*)d_in[7];
    const float* W1a_rel = (const float*)d_in[8];
    const float* W1a_root= (const float*)d_in[9];
    const float* b1a     = (const float*)d_in[10];
    const float* W2b_rel = (const float*)d_in[11];
    const float* W2b_root= (const float*)d_in[12];
    const float* b2b     = (const float*)d_in[13];
    const float* W2a_rel = (const float*)d_in[14];
    const float* W2a_root= (const float*)d_in[15];
    const float* b2a     = (const float*)d_in[16];
    const float* fcW     = (const float*)d_in[17];
    const float* fcb     = (const float*)d_in[18];
    float* out = (float*)d_out;

    char* ws = (char*)d_ws;
    size_t off = 0;
    auto alloc = [&](size_t bytes) {
        char* p = ws + off;
        off = (off + bytes + 255) & ~(size_t)255;
        return p;
    };
    __bf16* Wp1b = (__bf16*)alloc((size_t)512 * 256 * 2);   // K padded to 512
    __bf16* Wp1a = (__bf16*)alloc((size_t)2880 * 256 * 2);
    __bf16* Wp2b = (__bf16*)alloc((size_t)64 * 256 * 2);
    __bf16* Wp2a = (__bf16*)alloc((size_t)64 * 256 * 2);
    float*  bondT = (float*)alloc((size_t)13 * NNP * 4);    // row 12 = zeros
    float*  angleT= (float*)alloc((size_t)144 * NNP * 4);
    float*  Yb   = (float*)alloc((size_t)NN * 256 * 4);
    float*  Ya   = (float*)alloc((size_t)NN * 256 * 4);
    __bf16* Hbp  = (__bf16*)alloc((size_t)2 * MT2 * 512 * 2);
    __bf16* Hap  = (__bf16*)alloc((size_t)2 * MT2 * 512 * 2);
    int*    adj  = (int*)alloc((size_t)NN * 64 * 4);
    int*    deg  = (int*)alloc((size_t)NN * 4);
    float*  pooled = (float*)alloc((size_t)NCRYS * NSUB * 128 * 4);

    hipMemsetAsync(deg, 0, (size_t)NN * 4, stream);
    hipMemsetAsync(pooled, 0, (size_t)NCRYS * NSUB * 128 * 4, stream);

    setup_kernel<<<1822, 256, 0, stream>>>(species, nbr, adj, deg,
                                           W1b_rel, W1b_root, W1a_rel, W1a_root,
                                           W2b_rel, W2b_root, W2a_rel, W2a_root,
                                           Wp1b, Wp1a, Wp2b, Wp2a,
                                           bond, angle, bondT, angleT);

    mega_gemm1<<<628, 512, 0, stream>>>(bondT, angleT, Wp1b, Wp1a, Yb, Ya);
    agg_packed<<<dim3(5024, 2), 256, 0, stream>>>(Yb, Ya, adj, deg, b1b, b1a, Hbp, Hap);
    mega_gemm2<<<dim3(314, 2), 256, 0, stream>>>(Hbp, Hap, Wp2b, Wp2a, Yb, Ya);
    agg_pool<<<dim3(5000, 2), 256, 0, stream>>>(Yb, Ya, adj, deg, b2b, b2a, crys, pooled);
    final2<<<NCRYS * 2, 64, 0, stream>>>(pooled, crys, fcW, fcb, out);
}

// Round 9
// 262.925 us; speedup vs baseline: 1.0721x; 1.0721x over previous
//
#include <hip/hip_runtime.h>

#define NN 20000
#define NNP 20096       // padded rows: 314*64
#define NEIGH 12
#define NCRYS 20
#define MT2 1256        // padded M row-tiles of 16
#define NSUB 16         // pooled partial-sum split

typedef __bf16 bf16x8 __attribute__((ext_vector_type(8)));
typedef __bf16 bf16x4 __attribute__((ext_vector_type(4)));
typedef float f32x4 __attribute__((ext_vector_type(4)));

// ============================================================
// pack: W[k][n] -> bf16 MFMA-B frag layout Wp[kt][nt][k8][ni][j]
// ============================================================
__device__ __forceinline__ void pack_one(const float* Wrel, const float* Wroot,
                                         __bf16* Wp, int K, int idx) {
    int k = idx >> 8, n = idx & 255;
    int r = n >> 6, h = n & 63;
    float v = (r < 3) ? Wrel[((size_t)r * K + k) * 64 + h] : Wroot[(size_t)k * 64 + h];
    int kt = k >> 5, k8 = (k >> 3) & 3, j = k & 7, nt = n >> 4, ni = n & 15;
    Wp[((((size_t)kt * 16 + nt) * 4 + k8) * 16 + ni) * 8 + j] = (__bf16)v;
}

// ============================================================
// setup: build_adj (938) + pack (256, strided) + transpose (628)
// ============================================================
__global__ __launch_bounds__(256) void setup_kernel(
    const int* __restrict__ species, const int* __restrict__ nbr,
    int* __restrict__ adj, int* __restrict__ deg,
    const float* __restrict__ W1b_rel, const float* __restrict__ W1b_root,
    const float* __restrict__ W1a_rel, const float* __restrict__ W1a_root,
    const float* __restrict__ W2b_rel, const float* __restrict__ W2b_root,
    const float* __restrict__ W2a_rel, const float* __restrict__ W2a_root,
    __bf16* __restrict__ Wp1b, __bf16* __restrict__ Wp1a,
    __bf16* __restrict__ Wp2b, __bf16* __restrict__ Wp2a,
    const float* __restrict__ bond, const float* __restrict__ angle,
    float* __restrict__ bondT, float* __restrict__ angleT) {
    __shared__ float ls[64 * 145];
    const int bx = blockIdx.x, tid = threadIdx.x;
    if (bx < 938) {
        int e = bx * 256 + tid;
        if (e < NN * NEIGH) {
            int i = e / NEIGH;
            int d = nbr[e];
            int r = species[i] + species[d];
            int slot = atomicAdd(&deg[d], 1);
            if (slot < 64) adj[(size_t)d * 64 + slot] = i | (r << 28);
        }
    } else if (bx < 938 + 256) {
        const int S0 = 480 * 256, S1 = S0 + 2880 * 256, S2 = S1 + 64 * 256, S3 = S2 + 64 * 256;
        for (int idx = (bx - 938) * 256 + tid; idx < S3; idx += 256 * 256) {
            if (idx < S0)       pack_one(W1b_rel, W1b_root, Wp1b, 480, idx);
            else if (idx < S1)  pack_one(W1a_rel, W1a_root, Wp1a, 2880, idx - S0);
            else if (idx < S2)  pack_one(W2b_rel, W2b_root, Wp2b, 64, idx - S1);
            else                pack_one(W2a_rel, W2a_root, Wp2a, 64, idx - S2);
        }
    } else {
        int tb = bx - 1194;
        if (tb < 314) {
            int m0 = tb * 64;
            for (int idx = tid; idx < 64 * 144; idx += 256) {
                int mm = idx / 144, j = idx - mm * 144;
                int m = m0 + mm;
                ls[mm * 145 + j] = (m < NN) ? angle[(size_t)m * 144 + j] : 0.f;
            }
            __syncthreads();
            for (int idx = tid; idx < 144 * 64; idx += 256) {
                int j = idx >> 6, mm = idx & 63;
                angleT[(size_t)j * NNP + m0 + mm] = ls[mm * 145 + j];
            }
        } else {
            int m0 = (tb - 314) * 64;
            for (int idx = tid; idx < 64 * 12; idx += 256) {
                int mm = idx / 12, j = idx - mm * 12;
                int m = m0 + mm;
                ls[mm * 13 + j] = (m < NN) ? bond[(size_t)m * 12 + j] : 0.f;
            }
            __syncthreads();
            for (int idx = tid; idx < 12 * 64; idx += 256) {
                int j = idx >> 6, mm = idx & 63;
                bondT[(size_t)j * NNP + m0 + mm] = ls[mm * 13 + j];
            }
        }
    }
}

// ============================================================
// gemm1 (R7 structure, proven): 64x256 tile, 512 threads (8 waves, each
// 64r x 32c). BK=32, A gbf-recurrence LDS ping-pong, B global->frag regs
// with depth-2 prefetch.
// ============================================================
template <int MODE>  // 0: bond K=480 DIVN=40; 1: angle K=2880 DIVN=20
__device__ __forceinline__ void gemm1_body(const float* __restrict__ xT,
                                           const __bf16* __restrict__ Wp,
                                           float* __restrict__ Y, int mb,
                                           __bf16* __restrict__ Al) {
    constexpr int KTOT = (MODE == 0) ? 480 : 2880;
    constexpr int NKT = KTOT / 32;
    constexpr int DIVN = (MODE == 0) ? 40 : 20;
    constexpr float F0 = (MODE == 0) ? 0.f : -1.f;
    constexpr float FS = (MODE == 0) ? (8.f / 39.f) : (2.f / 19.f);
    constexpr float NG2 = ((MODE == 0) ? -25.f : -100.f) * 1.44269504f;
    const float C  = __builtin_amdgcn_exp2f(2.f * NG2 * FS * FS);
    const float P1 = NG2 * FS * FS;
    const float P2 = -2.f * NG2 * FS;

    const int tid = threadIdx.x;
    const int lane = tid & 63, wv = tid >> 6;
    const int m0 = mb * 64;
    const int smt = tid >> 7;
    const int sk8 = (tid >> 5) & 3;
    const int smi = (tid >> 1) & 15;
    const int sjh = (tid & 1) * 4;
    const int sgm = m0 + smt * 16 + smi;
    const int kk0 = sk8 * 8 + sjh;
    const int swoff = (((smt * 4 + sk8) * 16 + smi) * 8 + sjh);
    const int k8b = lane >> 4, nib = lane & 15;
    const bf16x8* Bg = (const bf16x8*)Wp;

    f32x4 acc[4][2] = {};
    bf16x8 bcur[2], bnx[2], bnx2[2];

    auto bload = [&](int kt, bf16x8* d) {
#pragma unroll
        for (int jf = 0; jf < 2; ++jf)
            d[jf] = Bg[(((size_t)kt * 16 + 2 * wv + jf) * 4 + k8b) * 16 + nib];
    };
    auto aload = [&](int kt) -> float {
        int k = kt * 32 + kk0;
        int jr = k / DIVN;
        return xT[(size_t)jr * NNP + sgm];
    };
    auto stage = [&](int kt, float a, __bf16* dst) {
        int k = kt * 32 + kk0;
        int jr = k / DIVN;
        int s = k - jr * DIVN;
        float d0 = a - (F0 + (float)s * FS);
        float e0 = __builtin_amdgcn_exp2f(NG2 * d0 * d0);
        float q0 = __builtin_amdgcn_exp2f(fmaf(P2, d0, P1));
        float e1 = e0 * q0;
        float q1 = q0 * C;
        float e2 = e1 * q1;
        float e3 = e2 * q1 * C;
        bf16x4 vals;
        vals[0] = (__bf16)e0; vals[1] = (__bf16)e1;
        vals[2] = (__bf16)e2; vals[3] = (__bf16)e3;
        *(bf16x4*)&dst[swoff] = vals;
    };

    {
        float a0 = aload(0);
        stage(0, a0, Al);
    }
    float anext = aload(1 < NKT ? 1 : 0);
    bload(0, bcur);
    bload(1 < NKT ? 1 : 0, bnx);
    __syncthreads();

    for (int kt = 0; kt < NKT; ++kt) {
        __bf16* Ab = Al + ((kt & 1) << 11);
        __bf16* An = Al + (((kt & 1) ^ 1) << 11);
        const int ktp2 = (kt + 2 < NKT) ? kt + 2 : NKT - 1;
        bload(ktp2, bnx2);
        float afut = (kt + 2 < NKT) ? aload(kt + 2) : anext;
        bf16x8 af[4];
#pragma unroll
        for (int t = 0; t < 4; ++t)
            af[t] = *(const bf16x8*)&Ab[((((t << 2) + k8b) << 4) + nib) << 3];
#pragma unroll
        for (int i = 0; i < 4; ++i)
#pragma unroll
            for (int j = 0; j < 2; ++j)
                acc[i][j] = __builtin_amdgcn_mfma_f32_16x16x32_bf16(af[i], bcur[j], acc[i][j], 0, 0, 0);
        if (kt + 1 < NKT)
            stage(kt + 1, anext, An);
        __syncthreads();
#pragma unroll
        for (int j = 0; j < 2; ++j) { bcur[j] = bnx[j]; bnx[j] = bnx2[j]; }
        anext = afut;
    }

    const int mrow0 = m0 + ((lane >> 4) << 2);
    const int ncol = (wv << 5) + nib;
#pragma unroll
    for (int i = 0; i < 4; ++i)
#pragma unroll
        for (int j = 0; j < 2; ++j)
#pragma unroll
            for (int v = 0; v < 4; ++v) {
                int m = mrow0 + i * 16 + v;
                if (m < NN) Y[(size_t)m * 256 + ncol + j * 16] = acc[i][j][v];
            }
}

__global__ __launch_bounds__(512, 4) void mega_gemm1(const float* __restrict__ bondT,
                                                     const float* __restrict__ angleT,
                                                     const __bf16* __restrict__ Wp1b,
                                                     const __bf16* __restrict__ Wp1a,
                                                     float* __restrict__ Yb, float* __restrict__ Ya) {
    __shared__ __align__(16) __bf16 Al[2 * 2048];
    int bx = blockIdx.x;
    if (bx < 314) gemm1_body<1>(angleT, Wp1a, Ya, bx, Al);
    else          gemm1_body<0>(bondT, Wp1b, Yb, bx - 314, Al);
}

// ============================================================
// Dense layer-2 GEMM, both chains. K=64, A pre-packed bf16, f32 out
// ============================================================
__global__ __launch_bounds__(256) void mega_gemm2(const __bf16* __restrict__ Hbp,
                                                  const __bf16* __restrict__ Hap,
                                                  const __bf16* __restrict__ Wp2b,
                                                  const __bf16* __restrict__ Wp2a,
                                                  float* __restrict__ Yb, float* __restrict__ Ya) {
    __shared__ __align__(16) __bf16 Al[4096];
    __shared__ __align__(16) __bf16 Bl[4096];
    const int ch = blockIdx.x & 1;
    const int mb = blockIdx.x >> 1;
    const int nb = blockIdx.y;
    const __bf16* Ap = ch ? Hap : Hbp;
    const __bf16* Wp = ch ? Wp2a : Wp2b;
    float* Y = ch ? Ya : Yb;
    const int tid = threadIdx.x;
    const int lane = tid & 63, wv = tid >> 6;
    const int m0 = mb * 128;
    const int rw = wv & 1, cw = wv >> 1;
    f32x4 acc[4][4] = {};
#pragma unroll
    for (int kt = 0; kt < 2; ++kt) {
        __syncthreads();
        {
            const float4* src = (const float4*)(Wp + (((size_t)kt * 16 + nb * 8) << 9));
            float4* dst = (float4*)Bl;
            float4 v0 = src[tid], v1 = src[tid + 256];
            dst[tid] = v0;
            dst[tid + 256] = v1;
        }
        {
            const float4* src = (const float4*)(Ap + (((size_t)kt * MT2 + mb * 8) << 9));
            float4* dst = (float4*)Al;
            float4 v0 = src[tid], v1 = src[tid + 256];
            dst[tid] = v0;
            dst[tid + 256] = v1;
        }
        __syncthreads();
        bf16x8 af[4], bfr[4];
        int fro = ((lane >> 4) << 4) + (lane & 15);
#pragma unroll
        for (int t4 = 0; t4 < 4; ++t4) {
            af[t4] = *(const bf16x8*)&Al[((((rw * 4 + t4) << 6) + fro) << 3)];
            bfr[t4] = *(const bf16x8*)&Bl[((((cw * 4 + t4) << 6) + fro) << 3)];
        }
#pragma unroll
        for (int i = 0; i < 4; ++i)
#pragma unroll
            for (int j = 0; j < 4; ++j)
                acc[i][j] = __builtin_amdgcn_mfma_f32_16x16x32_bf16(af[i], bfr[j], acc[i][j], 0, 0, 0);
    }
    const int n0 = nb * 128 + cw * 64;
    const int mrow0 = m0 + rw * 64 + ((lane >> 4) << 2);
    const int ncol = n0 + (lane & 15);
#pragma unroll
    for (int i = 0; i < 4; ++i)
#pragma unroll
        for (int j = 0; j < 4; ++j)
#pragma unroll
            for (int v = 0; v < 4; ++v) {
                int m = mrow0 + i * 16 + v;
                if (m < NN) Y[(size_t)m * 256 + ncol + j * 16] = acc[i][j][v];
            }
}

// ============================================================
// agg pair core: TWO nodes per wave — both adj/root loads and both 16-wide
// gather batches issued before any wait -> 32+ outstanding loads, one
// latency wall instead of two per node-pair.
// ============================================================
__device__ __forceinline__ void agg_pair(const float* __restrict__ Y,
                                         const int* __restrict__ adj,
                                         const int* __restrict__ deg,
                                         const float* __restrict__ bias,
                                         int nodeA, int nodeB, int h,
                                         float& oA, float& oB) {
    bool hasA = nodeA < NN, hasB = nodeB < NN;
    int dgA = hasA ? min(deg[nodeA], 64) : 0;
    int dgB = hasB ? min(deg[nodeB], 64) : 0;
    int eA = hasA ? adj[(size_t)nodeA * 64 + h] : 0;
    int eB = hasB ? adj[(size_t)nodeB * 64 + h] : 0;
    float rootA = hasA ? Y[(size_t)nodeA * 256 + 192 + h] : 0.f;
    float rootB = hasB ? Y[(size_t)nodeB * 256 + 192 + h] : 0.f;
    bool vA = h < dgA, vB = h < dgB;
    int rA = eA >> 28, rB = eB >> 28;
    int cA0 = __popcll(__ballot(vA && rA == 0));
    int cA1 = __popcll(__ballot(vA && rA == 1));
    int cA2 = __popcll(__ballot(vA && rA == 2));
    int cB0 = __popcll(__ballot(vB && rB == 0));
    int cB1 = __popcll(__ballot(vB && rB == 1));
    int cB2 = __popcll(__ballot(vB && rB == 2));
    int ecA = vA ? eA : 0;   // lanes >= dg fall back to edge 0 (safe addr)
    int ecB = vB ? eB : 0;
    float sA0 = 0.f, sA1 = 0.f, sA2 = 0.f, sB0 = 0.f, sB1 = 0.f, sB2 = 0.f;
    int maxdg = max(dgA, dgB);
    for (int k0 = 0; k0 < maxdg; k0 += 16) {
        float va[16], vb[16];
        int ea[16], eb[16];
        bool doA = k0 < dgA, doB = k0 < dgB;
        if (doA) {
#pragma unroll
            for (int i = 0; i < 16; ++i) {
                ea[i] = __builtin_amdgcn_readlane(ecA, k0 + i);
                va[i] = Y[(size_t)(ea[i] & 0x0FFFFFFF) * 256 + (ea[i] >> 28) * 64 + h];
            }
        }
        if (doB) {
#pragma unroll
            for (int i = 0; i < 16; ++i) {
                eb[i] = __builtin_amdgcn_readlane(ecB, k0 + i);
                vb[i] = Y[(size_t)(eb[i] & 0x0FFFFFFF) * 256 + (eb[i] >> 28) * 64 + h];
            }
        }
        if (doA) {
#pragma unroll
            for (int i = 0; i < 16; ++i) {
                if (k0 + i < dgA) {
                    int rr = ea[i] >> 28;
                    if (rr == 0) sA0 += va[i];
                    else if (rr == 1) sA1 += va[i];
                    else sA2 += va[i];
                }
            }
        }
        if (doB) {
#pragma unroll
            for (int i = 0; i < 16; ++i) {
                if (k0 + i < dgB) {
                    int rr = eb[i] >> 28;
                    if (rr == 0) sB0 += vb[i];
                    else if (rr == 1) sB1 += vb[i];
                    else sB2 += vb[i];
                }
            }
        }
    }
    float bh = bias[h];
    oA = hasA ? fmaxf(rootA + bh + sA0 / fmaxf((float)cA0, 1.f) +
                      sA1 / fmaxf((float)cA1, 1.f) + sA2 / fmaxf((float)cA2, 1.f), 0.f)
              : 0.f;
    oB = hasB ? fmaxf(rootB + bh + sB0 / fmaxf((float)cB0, 1.f) +
                      sB1 / fmaxf((float)cB1, 1.f) + sB2 / fmaxf((float)cB2, 1.f), 0.f)
              : 0.f;
}

// layer-1 agg -> bf16 packed-A frag layout (feeds mega_gemm2); 8 nodes/block
__global__ __launch_bounds__(256) void agg_packed(const float* __restrict__ Yb,
                                                  const float* __restrict__ Ya,
                                                  const int* __restrict__ adj,
                                                  const int* __restrict__ deg,
                                                  const float* __restrict__ biasb,
                                                  const float* __restrict__ biasa,
                                                  __bf16* __restrict__ outb,
                                                  __bf16* __restrict__ outa) {
    const float* Y = blockIdx.y ? Ya : Yb;
    const float* bias = blockIdx.y ? biasa : biasb;
    __bf16* outp = blockIdx.y ? outa : outb;
    int wv = threadIdx.x >> 6, h = threadIdx.x & 63;
    int nodeA = blockIdx.x * 8 + wv * 2, nodeB = nodeA + 1;
    float oA, oB;
    agg_pair(Y, adj, deg, bias, nodeA, nodeB, h, oA, oB);
    // packed-A layout: [kt][mt][k8][mi][j]; nodeA even -> same mt, mi differs by 1
    int mt = nodeA >> 4, mi = nodeA & 15;
    int ktt = h >> 5, k8 = (h >> 3) & 3, j = h & 7;
    size_t idx = ((((size_t)ktt * MT2 + mt) * 4 + k8) * 16 + mi) * 8 + j;
    outp[idx] = (__bf16)oA;
    outp[idx + 8] = (__bf16)oB;
}

// layer-2 agg fused with crystal pooling; 8 nodes/block
__global__ __launch_bounds__(256) void agg_pool(const float* __restrict__ Yb,
                                                const float* __restrict__ Ya,
                                                const int* __restrict__ adj,
                                                const int* __restrict__ deg,
                                                const float* __restrict__ biasb,
                                                const float* __restrict__ biasa,
                                                const int* __restrict__ crys,
                                                float* __restrict__ pooled) {
    const float* Y = blockIdx.y ? Ya : Yb;
    const float* bias = blockIdx.y ? biasa : biasb;
    const int base = blockIdx.y ? 64 : 0;
    int wv = threadIdx.x >> 6, h = threadIdx.x & 63;
    int nodeA = blockIdx.x * 8 + wv * 2, nodeB = nodeA + 1;
    float oA, oB;
    agg_pair(Y, adj, deg, bias, nodeA, nodeB, h, oA, oB);
    int cA = 0, cB = 0;
#pragma unroll
    for (int t = 1; t < NCRYS; ++t) {
        int st = crys[t * 2];
        cA += (nodeA >= st) ? 1 : 0;
        cB += (nodeB >= st) ? 1 : 0;
    }
    int sub = blockIdx.x & (NSUB - 1);
    if (nodeA < NN) atomicAdd(&pooled[((size_t)cA * NSUB + sub) * 128 + base + h], oA);
    if (nodeB < NN) atomicAdd(&pooled[((size_t)cB * NSUB + sub) * 128 + base + h], oB);
}

// ============================================================
// final: reduce partials, divide by count, FC
// ============================================================
__global__ void final2(const float* __restrict__ pooled, const int* __restrict__ crys,
                       const float* __restrict__ fcW, const float* __restrict__ fcb,
                       float* __restrict__ out) {
    int c = blockIdx.x >> 1, o = blockIdx.x & 1;
    int l = threadIdx.x;  // 0..63
    float cnt = (float)(crys[c * 2 + 1] - crys[c * 2]);
    float sb = 0.f, sa = 0.f;
    for (int s = 0; s < NSUB; ++s) {
        sb += pooled[((size_t)c * NSUB + s) * 128 + l];
        sa += pooled[((size_t)c * NSUB + s) * 128 + 64 + l];
    }
    float a = sb * fcW[l * 2 + o] + sa * fcW[(64 + l) * 2 + o];
    for (int s = 32; s > 0; s >>= 1) a += __shfl_down(a, s);
    if (l == 0) out[c * 2 + o] = a / cnt + fcb[o];
}

extern "C" void kernel_launch(void* const* d_in, const int* in_sizes, int n_in,
                              void* d_out, int out_size, void* d_ws, size_t ws_size,
                              hipStream_t stream) {
    const float* bond    = (const float*)d_in[0];
    const float* angle   = (const float*)d_in[1];
    const int*   species = (const int*)d_in[2];
    const int*   nbr     = (const int*)d_in[3];
    const int*   crys    = (const int*)d_in[4];
    const float* W1b_rel = (const float*)d_in[5];
    const float* W1b_root= (const float*)d_in[6];
    const float* b1b     = (const float*)d_in[7];
    const float* W1a_rel = (const float*)d_in[8];
    const float* W1a_root= (const float*)d_in[9];
    const float* b1a     = (const float*)d_in[10];
    const float* W2b_rel = (const float*)d_in[11];
    const float* W2b_root= (const float*)d_in[12];
    const float* b2b     = (const float*)d_in[13];
    const float* W2a_rel = (const float*)d_in[14];
    const float* W2a_root= (const float*)d_in[15];
    const float* b2a     = (const float*)d_in[16];
    const float* fcW     = (const float*)d_in[17];
    const float* fcb     = (const float*)d_in[18];
    float* out = (float*)d_out;

    char* ws = (char*)d_ws;
    size_t off = 0;
    auto alloc = [&](size_t bytes) {
        char* p = ws + off;
        off = (off + bytes + 255) & ~(size_t)255;
        return p;
    };
    __bf16* Wp1b = (__bf16*)alloc((size_t)480 * 256 * 2);
    __bf16* Wp1a = (__bf16*)alloc((size_t)2880 * 256 * 2);
    __bf16* Wp2b = (__bf16*)alloc((size_t)64 * 256 * 2);
    __bf16* Wp2a = (__bf16*)alloc((size_t)64 * 256 * 2);
    float*  bondT = (float*)alloc((size_t)12 * NNP * 4);
    float*  angleT= (float*)alloc((size_t)144 * NNP * 4);
    float*  Yb   = (float*)alloc((size_t)NN * 256 * 4);
    float*  Ya   = (float*)alloc((size_t)NN * 256 * 4);
    __bf16* Hbp  = (__bf16*)alloc((size_t)2 * MT2 * 512 * 2);
    __bf16* Hap  = (__bf16*)alloc((size_t)2 * MT2 * 512 * 2);
    int*    adj  = (int*)alloc((size_t)NN * 64 * 4);
    int*    deg  = (int*)alloc((size_t)NN * 4);
    float*  pooled = (float*)alloc((size_t)NCRYS * NSUB * 128 * 4);

    hipMemsetAsync(deg, 0, (size_t)NN * 4, stream);
    hipMemsetAsync(pooled, 0, (size_t)NCRYS * NSUB * 128 * 4, stream);

    setup_kernel<<<1822, 256, 0, stream>>>(species, nbr, adj, deg,
                                           W1b_rel, W1b_root, W1a_rel, W1a_root,
                                           W2b_rel, W2b_root, W2a_rel, W2a_root,
                                           Wp1b, Wp1a, Wp2b, Wp2a,
                                           bond, angle, bondT, angleT);

    mega_gemm1<<<628, 512, 0, stream>>>(bondT, angleT, Wp1b, Wp1a, Yb, Ya);
    agg_packed<<<dim3(2512, 2), 256, 0, stream>>>(Yb, Ya, adj, deg, b1b, b1a, Hbp, Hap);
    mega_gemm2<<<dim3(314, 2), 256, 0, stream>>>(Hbp, Hap, Wp2b, Wp2a, Yb, Ya);
    agg_pool<<<dim3(2500, 2), 256, 0, stream>>>(Yb, Ya, adj, deg, b2b, b2a, crys, pooled);
    final2<<<NCRYS * 2, 64, 0, stream>>>(pooled, crys, fcW, fcb, out);
}